// Round 1
// baseline (706.488 us; speedup 1.0000x reference)
//
#include <hip/hip_runtime.h>
#include <math.h>

#define NV 300
#define NA 12
#define ND 4
#define NB 2
#define NC 512
#define NSD 2048
#define NGP 2000
#define ROWLEN 14400  // NV*NA*ND

// ---------------------------------------------------------------- k_setup
// views (300x3), views_rot (300x3x3) = viewpoint_params_to_matrix(-views, 0),
// init global max/min slots.
__global__ void k_setup(float* __restrict__ views, float* __restrict__ views_rot,
                        int* __restrict__ mmx) {
  int i = threadIdx.x;
  if (i == 0) { mmx[0] = 0; mmx[1] = 0x7f800000; }  // umax=0.0f, umin=+inf
  if (i >= NV) return;
  float fi = (float)i;
  float Z = (2.0f * fi + 1.0f) / 300.0f - 1.0f;
  float r = sqrtf(fmaxf(1.0f - Z * Z, 0.0f));
  // JAX: ((2.0*pi) * i) * phi, all f32
  float ang = (6.28318530717958647692f * fi) * 0.61803398874989484820f;
  float X = r * cosf(ang);
  float Y = r * sinf(ang);
  views[i * 3 + 0] = X; views[i * 3 + 1] = Y; views[i * 3 + 2] = Z;
  // towards = -view
  float ax0 = -X, ax1 = -Y, ax2 = -Z;
  float ay0 = -ax1, ay1 = ax0, ay2 = 0.f;      // from UNNORMALIZED ax
  float ynorm = sqrtf(ay0 * ay0 + ay1 * ay1 + ay2 * ay2);
  if (ynorm == 0.f) { ay0 = 0.f; ay1 = 1.f; ay2 = 0.f; }
  float an = sqrtf(ax0 * ax0 + ax1 * ax1 + ax2 * ax2);
  ax0 /= an; ax1 /= an; ax2 /= an;
  float ayn = sqrtf(ay0 * ay0 + ay1 * ay1 + ay2 * ay2);
  ay0 /= ayn; ay1 /= ayn; ay2 /= ayn;
  float az0 = ax1 * ay2 - ax2 * ay1;
  float az1 = ax2 * ay0 - ax0 * ay2;
  float az2 = ax0 * ay1 - ax1 * ay0;
  float* m = views_rot + i * 9;  // columns ax, ay, az
  m[0] = ax0; m[1] = ay0; m[2] = az0;
  m[3] = ax1; m[4] = ay1; m[5] = az1;
  m[6] = ax2; m[7] = ay2; m[8] = az2;
}

// ---------------------------------------------------------------- k_batch_setup
// per batch: view_inds = knn1(views, views @ R^T); Rsel[v] = R @ views_rot[view_inds[v]]
__global__ void __launch_bounds__(512) k_batch_setup(
    const float* __restrict__ pose, const float* __restrict__ views,
    const float* __restrict__ views_rot, int* __restrict__ view_inds,
    float* __restrict__ Rsel) {
  int b = blockIdx.x, tid = threadIdx.x;
  __shared__ float R[9];
  __shared__ float gv[NV][3];
  __shared__ float gvr[NV];
  if (tid < 9) R[tid] = pose[b * 12 + (tid / 3) * 4 + (tid % 3)];
  __syncthreads();
  if (tid < NV) {
    float vx = views[tid * 3], vy = views[tid * 3 + 1], vz = views[tid * 3 + 2];
    float x = R[0] * vx + R[1] * vy + R[2] * vz;
    float y = R[3] * vx + R[4] * vy + R[5] * vz;
    float z = R[6] * vx + R[7] * vy + R[8] * vz;
    gv[tid][0] = x; gv[tid][1] = y; gv[tid][2] = z;
    gvr[tid] = x * x + y * y + z * z;
  }
  __syncthreads();
  if (tid < NV) {
    float qx = views[tid * 3], qy = views[tid * 3 + 1], qz = views[tid * 3 + 2];
    float qq = qx * qx + qy * qy + qz * qz;
    float best = INFINITY; int bi = 0;
    for (int u = 0; u < NV; u++) {
      float dot = qx * gv[u][0] + qy * gv[u][1] + qz * gv[u][2];
      float d = qq + gvr[u] - 2.f * dot;
      if (d < best) { best = d; bi = u; }
    }
    view_inds[b * NV + tid] = bi;
    const float* vr = views_rot + bi * 9;
    float* o = Rsel + (b * NV + tid) * 9;
    for (int i = 0; i < 3; i++)
      for (int j = 0; j < 3; j++)
        o[i * 3 + j] = R[i * 3 + 0] * vr[0 + j] + R[i * 3 + 1] * vr[3 + j] + R[i * 3 + 2] * vr[6 + j];
  }
}

// ---------------------------------------------------------------- k_gp_trans
__global__ void k_gp_trans(const float* __restrict__ pose,
                           const float* __restrict__ gpoints,
                           float* __restrict__ gpt, float* __restrict__ grr) {
  int idx = blockIdx.x * 256 + threadIdx.x;
  if (idx >= NB * NGP) return;
  int b = idx / NGP;
  const float* P = pose + b * 12;
  float px = gpoints[(size_t)idx * 3 + 0];
  float py = gpoints[(size_t)idx * 3 + 1];
  float pz = gpoints[(size_t)idx * 3 + 2];
  float x = P[0] * px + P[1] * py + P[2] * pz + P[3];
  float y = P[4] * px + P[5] * py + P[6] * pz + P[7];
  float z = P[8] * px + P[9] * py + P[10] * pz + P[11];
  gpt[(size_t)idx * 3 + 0] = x;
  gpt[(size_t)idx * 3 + 1] = y;
  gpt[(size_t)idx * 3 + 2] = z;
  grr[idx] = x * x + y * y + z * z;
}

// ---------------------------------------------------------------- k_nn
// nn_inds = knn1(point_clouds[b], gp_trans[b]); gp output gather.
__global__ void __launch_bounds__(256) k_nn(
    const float* __restrict__ pc, const float* __restrict__ gpt,
    const float* __restrict__ grr, int* __restrict__ nn_inds,
    float* __restrict__ out_gp) {
  int b = blockIdx.y;
  int s = blockIdx.x * 256 + threadIdx.x;
  __shared__ float gx[NGP], gy[NGP], gz[NGP], gr[NGP];
  for (int i = threadIdx.x; i < NGP; i += 256) {
    gx[i] = gpt[((size_t)b * NGP + i) * 3 + 0];
    gy[i] = gpt[((size_t)b * NGP + i) * 3 + 1];
    gz[i] = gpt[((size_t)b * NGP + i) * 3 + 2];
    gr[i] = grr[b * NGP + i];
  }
  __syncthreads();
  float qx = pc[((size_t)b * NSD + s) * 3 + 0];
  float qy = pc[((size_t)b * NSD + s) * 3 + 1];
  float qz = pc[((size_t)b * NSD + s) * 3 + 2];
  float qq = qx * qx + qy * qy + qz * qz;
  float best = INFINITY; int bi = 0;
  for (int i = 0; i < NGP; i++) {
    float dot = qx * gx[i] + qy * gy[i] + qz * gz[i];
    float d = qq + gr[i] - 2.f * dot;
    if (d < best) { best = d; bi = i; }
  }
  nn_inds[b * NSD + s] = bi;
  out_gp[((size_t)b * NSD + s) * 3 + 0] = gx[bi];
  out_gp[((size_t)b * NSD + s) * 3 + 1] = gy[bi];
  out_gp[((size_t)b * NSD + s) * 3 + 2] = gz[bi];
}

// ---------------------------------------------------------------- gemm
// Y[b][o][n] = sum_i W[o][i] * X[b][i][n] + bias[o]  (optional relu)
// 64x64 tile, BK=16, 256 threads, 4x4 micro-tile. fp32 (no fp32 MFMA on CDNA4;
// bf16 would risk argmax flips in view_scores).
template <bool RELU, bool GUARD_M>
__global__ void __launch_bounds__(256) gemm_k(
    const float* __restrict__ W, const float* __restrict__ X,
    const float* __restrict__ bias, float* __restrict__ Y,
    int O, int Cin, int N) {
  int b = blockIdx.z;
  const float* Xb = X + (size_t)b * Cin * N;
  float* Yb = Y + (size_t)b * O * N;
  int m0 = blockIdx.y * 64, n0 = blockIdx.x * 64;
  __shared__ float As[16][68];  // [k][m], padded
  __shared__ float Bs[16][64];  // [k][n]
  int tid = threadIdx.x;
  int mW = tid >> 2, kW = (tid & 3) * 4;
  int kX = tid >> 4, nX = (tid & 15) * 4;
  int ty = tid >> 4, tx = tid & 15;
  float acc[4][4] = {};
  for (int k0 = 0; k0 < Cin; k0 += 16) {
    float4 wv;
    if (!GUARD_M || (m0 + mW) < O)
      wv = *(const float4*)&W[(size_t)(m0 + mW) * Cin + k0 + kW];
    else
      wv = make_float4(0.f, 0.f, 0.f, 0.f);
    As[kW + 0][mW] = wv.x; As[kW + 1][mW] = wv.y;
    As[kW + 2][mW] = wv.z; As[kW + 3][mW] = wv.w;
    *(float4*)&Bs[kX][nX] = *(const float4*)&Xb[(size_t)(k0 + kX) * N + n0 + nX];
    __syncthreads();
#pragma unroll
    for (int kk = 0; kk < 16; kk++) {
      float4 a = *(const float4*)&As[kk][ty << 2];
      float4 bv = *(const float4*)&Bs[kk][tx << 2];
      acc[0][0] = fmaf(a.x, bv.x, acc[0][0]); acc[0][1] = fmaf(a.x, bv.y, acc[0][1]);
      acc[0][2] = fmaf(a.x, bv.z, acc[0][2]); acc[0][3] = fmaf(a.x, bv.w, acc[0][3]);
      acc[1][0] = fmaf(a.y, bv.x, acc[1][0]); acc[1][1] = fmaf(a.y, bv.y, acc[1][1]);
      acc[1][2] = fmaf(a.y, bv.z, acc[1][2]); acc[1][3] = fmaf(a.y, bv.w, acc[1][3]);
      acc[2][0] = fmaf(a.z, bv.x, acc[2][0]); acc[2][1] = fmaf(a.z, bv.y, acc[2][1]);
      acc[2][2] = fmaf(a.z, bv.z, acc[2][2]); acc[2][3] = fmaf(a.z, bv.w, acc[2][3]);
      acc[3][0] = fmaf(a.w, bv.x, acc[3][0]); acc[3][1] = fmaf(a.w, bv.y, acc[3][1]);
      acc[3][2] = fmaf(a.w, bv.z, acc[3][2]); acc[3][3] = fmaf(a.w, bv.w, acc[3][3]);
    }
    __syncthreads();
  }
#pragma unroll
  for (int i = 0; i < 4; i++) {
    int m = m0 + ty * 4 + i;
    if (GUARD_M && m >= O) break;
    float bi = bias[m];
    float4 v;
    v.x = acc[i][0] + bi; v.y = acc[i][1] + bi;
    v.z = acc[i][2] + bi; v.w = acc[i][3] + bi;
    if (RELU) {
      v.x = fmaxf(v.x, 0.f); v.y = fmaxf(v.y, 0.f);
      v.z = fmaxf(v.z, 0.f); v.w = fmaxf(v.w, 0.f);
    }
    *(float4*)&Yb[(size_t)m * N + n0 + (tx << 2)] = v;
  }
}

// ---------------------------------------------------------------- k_argmax
// per (b,n): argmax over 300 views (first-occurrence); gather vp_rot & top_rot.
__global__ void __launch_bounds__(256) k_argmax(
    const float* __restrict__ vs_t, const float* __restrict__ views_rot,
    const float* __restrict__ Rsel, int* __restrict__ tv_inds,
    float* __restrict__ o_vprot, float* __restrict__ o_trot) {
  int b = blockIdx.y;
  int n = blockIdx.x * 256 + threadIdx.x;
  const float* src = vs_t + (size_t)b * NV * NSD + n;
  float best = src[0]; int bi = 0;
  for (int v = 1; v < NV; v++) {
    float val = src[(size_t)v * NSD];
    if (val > best) { best = val; bi = v; }
  }
  tv_inds[b * NSD + n] = bi;
  const float* vr = views_rot + bi * 9;
  float* o1 = o_vprot + ((size_t)b * NSD + n) * 9;
  const float* rs = Rsel + (b * NV + bi) * 9;
  float* o4 = o_trot + ((size_t)b * NSD + n) * 9;
#pragma unroll
  for (int i = 0; i < 9; i++) { o1[i] = vr[i]; o4[i] = rs[i]; }
}

// ---------------------------------------------------------------- k_transpose_vs
__global__ void k_transpose_vs(const float* __restrict__ vs_t, float* __restrict__ out) {
  __shared__ float tile[32][33];
  int b = blockIdx.z;
  int v0 = blockIdx.x * 32, n0 = blockIdx.y * 32;
  const float* src = vs_t + (size_t)b * NV * NSD;
  for (int i = threadIdx.y; i < 32; i += 8) {
    int v = v0 + i;
    if (v < NV) tile[i][threadIdx.x] = src[(size_t)v * NSD + n0 + threadIdx.x];
  }
  __syncthreads();
  for (int i = threadIdx.y; i < 32; i += 8) {
    int n = n0 + i;
    int v = v0 + threadIdx.x;
    if (v < NV) out[((size_t)b * NSD + n) * NV + v] = tile[threadIdx.x][i];
  }
}

// ---------------------------------------------------------------- k_f2
// f2 (B,96,N) -> gsp (B,N,48) [ch 0..47], gwp (B,N,48) [ch 48..95]
__global__ void __launch_bounds__(256) k_f2(const float* __restrict__ f2,
                                            float* __restrict__ gsp,
                                            float* __restrict__ gwp) {
  __shared__ float tile[96][65];
  int b = blockIdx.y, n0 = blockIdx.x * 64;
  const float* src = f2 + (size_t)b * 96 * NSD;
  for (int idx = threadIdx.x; idx < 96 * 64; idx += 256) {
    int ch = idx >> 6, j = idx & 63;
    tile[ch][j] = src[(size_t)ch * NSD + n0 + j];
  }
  __syncthreads();
  for (int idx = threadIdx.x; idx < 64 * 48; idx += 256) {
    int j = idx / 48, ad = idx % 48;
    size_t o = ((size_t)b * NSD + n0 + j) * 48 + ad;
    gsp[o] = tile[ad][j];
    gwp[o] = tile[48 + ad][j];
  }
}

// ---------------------------------------------------------------- k_grasp
// per (b,s): graspness over 300 views (normalized), top_wd out, masked top_sc raw.
__global__ void __launch_bounds__(256) k_grasp(
    const float* __restrict__ gscores, const float* __restrict__ goffsets,
    const int* __restrict__ nn_inds, const int* __restrict__ tv_inds,
    const int* __restrict__ view_inds, float* __restrict__ o_grsp,
    float* __restrict__ o_twd, float* __restrict__ raw) {
  int b = blockIdx.y, s = blockIdx.x, tid = threadIdx.x;
  int nn = nn_inds[b * NSD + s];
  int tv = tv_inds[b * NSD + s];
  int vit = view_inds[b * NV + tv];
  const float* srow = gscores + ((size_t)(b * NGP + nn)) * ROWLEN;
  const float* wrow = goffsets + ((size_t)(b * NGP + nn)) * ROWLEN;
  if (tid < 48) {
    float sc = srow[vit * 48 + tid];
    float wd = wrow[vit * 48 + tid];
    bool m = (sc > 0.f) && (wd <= 0.1f);
    o_twd[((size_t)b * NSD + s) * 48 + tid] = wd;
    raw[((size_t)b * NSD + s) * 48 + tid] = m ? sc : 0.f;
  }
  __shared__ float g[NV];
  for (int v = tid; v < NV; v += 256) {
    int vv = view_inds[b * NV + v];
    const float4* p = (const float4*)(srow + vv * 48);
    int cnt = 0;
#pragma unroll
    for (int q = 0; q < 12; q++) {
      float4 x = p[q];
      cnt += (x.x > 0.f && x.x <= 0.6f);
      cnt += (x.y > 0.f && x.y <= 0.6f);
      cnt += (x.z > 0.f && x.z <= 0.6f);
      cnt += (x.w > 0.f && x.w <= 0.6f);
    }
    g[v] = (float)cnt / 48.0f;
  }
  __syncthreads();
  float mx = -INFINITY, mn = INFINITY;
  for (int v = tid; v < NV; v += 256) { mx = fmaxf(mx, g[v]); mn = fminf(mn, g[v]); }
  for (int off = 32; off; off >>= 1) {
    mx = fmaxf(mx, __shfl_down(mx, off));
    mn = fminf(mn, __shfl_down(mn, off));
  }
  __shared__ float wmx[4], wmn[4];
  int wid = tid >> 6, lane = tid & 63;
  if (lane == 0) { wmx[wid] = mx; wmn[wid] = mn; }
  __syncthreads();
  if (tid == 0) {
    mx = fmaxf(fmaxf(wmx[0], wmx[1]), fmaxf(wmx[2], wmx[3]));
    mn = fminf(fminf(wmn[0], wmn[1]), fminf(wmn[2], wmn[3]));
    wmx[0] = mx; wmn[0] = mn;
  }
  __syncthreads();
  mx = wmx[0]; mn = wmn[0];
  float denom = mx - mn + 1e-8f;
  float* og = o_grsp + ((size_t)b * NSD + s) * NV;
  for (int v = tid; v < NV; v += 256) og[v] = (g[v] - mn) / denom;
}

// ---------------------------------------------------------------- k_reduce
__global__ void __launch_bounds__(256) k_reduce(const float* __restrict__ raw,
                                                int n, int* __restrict__ mmx) {
  float mx = -INFINITY, mn = INFINITY;
  for (int i = blockIdx.x * 256 + threadIdx.x; i < n; i += gridDim.x * 256) {
    float v = raw[i];
    mx = fmaxf(mx, v);
    if (v > 0.f) mn = fminf(mn, v);
  }
  for (int off = 32; off; off >>= 1) {
    mx = fmaxf(mx, __shfl_down(mx, off));
    mn = fminf(mn, __shfl_down(mn, off));
  }
  __shared__ float smx[4], smn[4];
  int wid = threadIdx.x >> 6, lane = threadIdx.x & 63;
  if (lane == 0) { smx[wid] = mx; smn[wid] = mn; }
  __syncthreads();
  if (threadIdx.x == 0) {
    mx = fmaxf(fmaxf(smx[0], smx[1]), fmaxf(smx[2], smx[3]));
    mn = fminf(fminf(smn[0], smn[1]), fminf(smn[2], smn[3]));
    atomicMax(&mmx[0], __float_as_int(mx));          // values >= 0: int order == float order
    if (mn != INFINITY) atomicMin(&mmx[1], __float_as_int(mn));
  }
}

// ---------------------------------------------------------------- k_topsc
__global__ void k_topsc(const float* __restrict__ raw, const int* __restrict__ mmx,
                        float* __restrict__ out, int n) {
  int i = blockIdx.x * 256 + threadIdx.x;
  if (i >= n) return;
  float sc = raw[i];
  float umax = __int_as_float(mmx[0]);
  float umin = __int_as_float(mmx[1]);
  float denom = logf(umax / umin) + 1e-8f;
  float val = logf(umax / sc) / denom;
  out[i] = (sc > 0.f) ? val : sc;
}

// ================================================================ launch
extern "C" void kernel_launch(void* const* d_in, const int* in_sizes, int n_in,
                              void* d_out, int out_size, void* d_ws, size_t ws_size,
                              hipStream_t stream) {
  const float* seed_features = (const float*)d_in[0];
  const float* point_clouds  = (const float*)d_in[1];
  const float* object_pose   = (const float*)d_in[2];
  const float* grasp_points  = (const float*)d_in[3];
  const float* grasp_labels  = (const float*)d_in[4];
  const float* grasp_offsets = (const float*)d_in[5];
  const float* aw1_w = (const float*)d_in[6];
  const float* aw1_b = (const float*)d_in[7];
  const float* aw2_w = (const float*)d_in[8];
  const float* aw2_b = (const float*)d_in[9];
  const float* aw3_w = (const float*)d_in[10];
  const float* aw3_b = (const float*)d_in[11];
  const float* sw1_w = (const float*)d_in[12];
  const float* sw1_b = (const float*)d_in[13];
  const float* sw2_w = (const float*)d_in[14];
  const float* sw2_b = (const float*)d_in[15];

  float* out = (float*)d_out;
  float* o_vs    = out;                      // (B,NS,300)
  float* o_vprot = o_vs + NB * NSD * NV;     // (B,NS,3,3)
  float* o_gsp   = o_vprot + NB * NSD * 9;   // (B,NS,12,4)
  float* o_gwp   = o_gsp + NB * NSD * 48;
  float* o_trot  = o_gwp + NB * NSD * 48;    // (B,NS,3,3)
  float* o_tsc   = o_trot + NB * NSD * 9;
  float* o_twd   = o_tsc + NB * NSD * 48;
  float* o_grsp  = o_twd + NB * NSD * 48;    // (B,NS,300)
  float* o_gp    = o_grsp + NB * NSD * NV;   // (B,NS,3)

  float* w = (float*)d_ws;
  float* res1 = w; w += NB * NC * NSD;       // reused as f1
  float* res2 = w; w += NB * NC * NSD;
  float* vs_t = w; w += NB * NV * NSD;
  float* f2   = w; w += NB * 96 * NSD;
  float* views = w; w += 960;
  float* views_rot = w; w += 2720;
  float* gpt = w; w += NB * NGP * 3;
  float* grr = w; w += NB * NGP;
  float* Rsel = w; w += NB * NV * 9;
  float* raw  = w; w += NB * NSD * 48;
  int* view_inds = (int*)w; w += NB * NV;
  int* nn_inds   = (int*)w; w += NB * NSD;
  int* tv_inds   = (int*)w; w += NB * NSD;
  int* mmx       = (int*)w; w += 8;

  k_setup<<<1, 512, 0, stream>>>(views, views_rot, mmx);
  k_batch_setup<<<NB, 512, 0, stream>>>(object_pose, views, views_rot, view_inds, Rsel);
  k_gp_trans<<<(NB * NGP + 255) / 256, 256, 0, stream>>>(object_pose, grasp_points, gpt, grr);
  k_nn<<<dim3(NSD / 256, NB), 256, 0, stream>>>(point_clouds, gpt, grr, nn_inds, o_gp);

  gemm_k<true, false><<<dim3(NSD / 64, NC / 64, NB), 256, 0, stream>>>(
      aw1_w, seed_features, aw1_b, res1, NC, NC, NSD);
  gemm_k<true, false><<<dim3(NSD / 64, NC / 64, NB), 256, 0, stream>>>(
      aw2_w, res1, aw2_b, res2, NC, NC, NSD);
  gemm_k<false, true><<<dim3(NSD / 64, (NV + 63) / 64, NB), 256, 0, stream>>>(
      aw3_w, res2, aw3_b, vs_t, NV, NC, NSD);
  gemm_k<true, false><<<dim3(NSD / 64, NC / 64, NB), 256, 0, stream>>>(
      sw1_w, res2, sw1_b, res1, NC, NC, NSD);
  gemm_k<false, true><<<dim3(NSD / 64, (96 + 63) / 64, NB), 256, 0, stream>>>(
      sw2_w, res1, sw2_b, f2, 96, NC, NSD);

  k_argmax<<<dim3(NSD / 256, NB), 256, 0, stream>>>(vs_t, views_rot, Rsel, tv_inds,
                                                    o_vprot, o_trot);
  k_transpose_vs<<<dim3((NV + 31) / 32, NSD / 32, NB), dim3(32, 8), 0, stream>>>(vs_t, o_vs);
  k_f2<<<dim3(NSD / 64, NB), 256, 0, stream>>>(f2, o_gsp, o_gwp);
  k_grasp<<<dim3(NSD, NB), 256, 0, stream>>>(grasp_labels, grasp_offsets, nn_inds,
                                             tv_inds, view_inds, o_grsp, o_twd, raw);
  k_reduce<<<256, 256, 0, stream>>>(raw, NB * NSD * 48, mmx);
  k_topsc<<<(NB * NSD * 48 + 255) / 256, 256, 0, stream>>>(raw, mmx, o_tsc, NB * NSD * 48);
}

// Round 2
// 655.498 us; speedup vs baseline: 1.0778x; 1.0778x over previous
//
#include <hip/hip_runtime.h>
#include <math.h>

#define NV 300
#define NA 12
#define ND 4
#define NB 2
#define NC 512
#define NSD 2048
#define NGP 2000
#define ROWLEN 14400  // NV*NA*ND

// ---------------------------------------------------------------- k_setup
__global__ void k_setup(float* __restrict__ views, float* __restrict__ views_rot,
                        int* __restrict__ mmx) {
  int i = threadIdx.x;
  if (i == 0) { mmx[0] = 0; mmx[1] = 0x7f800000; }  // umax=0.0f, umin=+inf
  if (i >= NV) return;
  float fi = (float)i;
  float Z = (2.0f * fi + 1.0f) / 300.0f - 1.0f;
  float r = sqrtf(fmaxf(1.0f - Z * Z, 0.0f));
  float ang = (6.28318530717958647692f * fi) * 0.61803398874989484820f;
  float X = r * cosf(ang);
  float Y = r * sinf(ang);
  views[i * 3 + 0] = X; views[i * 3 + 1] = Y; views[i * 3 + 2] = Z;
  float ax0 = -X, ax1 = -Y, ax2 = -Z;
  float ay0 = -ax1, ay1 = ax0, ay2 = 0.f;      // from UNNORMALIZED ax
  float ynorm = sqrtf(ay0 * ay0 + ay1 * ay1 + ay2 * ay2);
  if (ynorm == 0.f) { ay0 = 0.f; ay1 = 1.f; ay2 = 0.f; }
  float an = sqrtf(ax0 * ax0 + ax1 * ax1 + ax2 * ax2);
  ax0 /= an; ax1 /= an; ax2 /= an;
  float ayn = sqrtf(ay0 * ay0 + ay1 * ay1 + ay2 * ay2);
  ay0 /= ayn; ay1 /= ayn; ay2 /= ayn;
  float az0 = ax1 * ay2 - ax2 * ay1;
  float az1 = ax2 * ay0 - ax0 * ay2;
  float az2 = ax0 * ay1 - ax1 * ay0;
  float* m = views_rot + i * 9;  // columns ax, ay, az
  m[0] = ax0; m[1] = ay0; m[2] = az0;
  m[3] = ax1; m[4] = ay1; m[5] = az1;
  m[6] = ax2; m[7] = ay2; m[8] = az2;
}

// ---------------------------------------------------------------- k_batch_setup
__global__ void __launch_bounds__(512) k_batch_setup(
    const float* __restrict__ pose, const float* __restrict__ views,
    const float* __restrict__ views_rot, int* __restrict__ view_inds,
    float* __restrict__ Rsel) {
  int b = blockIdx.x, tid = threadIdx.x;
  __shared__ float R[9];
  __shared__ float gv[NV][3];
  __shared__ float gvr[NV];
  if (tid < 9) R[tid] = pose[b * 12 + (tid / 3) * 4 + (tid % 3)];
  __syncthreads();
  if (tid < NV) {
    float vx = views[tid * 3], vy = views[tid * 3 + 1], vz = views[tid * 3 + 2];
    float x = R[0] * vx + R[1] * vy + R[2] * vz;
    float y = R[3] * vx + R[4] * vy + R[5] * vz;
    float z = R[6] * vx + R[7] * vy + R[8] * vz;
    gv[tid][0] = x; gv[tid][1] = y; gv[tid][2] = z;
    gvr[tid] = x * x + y * y + z * z;
  }
  __syncthreads();
  if (tid < NV) {
    float qx = views[tid * 3], qy = views[tid * 3 + 1], qz = views[tid * 3 + 2];
    float qq = qx * qx + qy * qy + qz * qz;
    float best = INFINITY; int bi = 0;
    for (int u = 0; u < NV; u++) {
      float dot = qx * gv[u][0] + qy * gv[u][1] + qz * gv[u][2];
      float d = qq + gvr[u] - 2.f * dot;
      if (d < best) { best = d; bi = u; }
    }
    view_inds[b * NV + tid] = bi;
    const float* vr = views_rot + bi * 9;
    float* o = Rsel + (b * NV + tid) * 9;
    for (int i = 0; i < 3; i++)
      for (int j = 0; j < 3; j++)
        o[i * 3 + j] = R[i * 3 + 0] * vr[0 + j] + R[i * 3 + 1] * vr[3 + j] + R[i * 3 + 2] * vr[6 + j];
  }
}

// ---------------------------------------------------------------- k_gp_trans
// writes float4 {x, y, z, x^2+y^2+z^2}
__global__ void k_gp_trans(const float* __restrict__ pose,
                           const float* __restrict__ gpoints,
                           float4* __restrict__ gpt4) {
  int idx = blockIdx.x * 256 + threadIdx.x;
  if (idx >= NB * NGP) return;
  int b = idx / NGP;
  const float* P = pose + b * 12;
  float px = gpoints[(size_t)idx * 3 + 0];
  float py = gpoints[(size_t)idx * 3 + 1];
  float pz = gpoints[(size_t)idx * 3 + 2];
  float x = P[0] * px + P[1] * py + P[2] * pz + P[3];
  float y = P[4] * px + P[5] * py + P[6] * pz + P[7];
  float z = P[8] * px + P[9] * py + P[10] * pz + P[11];
  gpt4[idx] = make_float4(x, y, z, x * x + y * y + z * z);
}

// ---------------------------------------------------------------- k_nn
// 128 blocks: each block = 32 seeds x 8 chunks of 250 points.
__global__ void __launch_bounds__(256) k_nn(
    const float* __restrict__ pc, const float4* __restrict__ gpt4,
    int* __restrict__ nn_inds, float* __restrict__ out_gp) {
  int b = blockIdx.y;
  int s0 = blockIdx.x * 32;
  int tid = threadIdx.x;
  __shared__ float4 pts[NGP];          // 32 KB
  for (int i = tid; i < NGP; i += 256) pts[i] = gpt4[b * NGP + i];
  __syncthreads();
  int sl = tid & 31, chunk = tid >> 5;
  int s = s0 + sl;
  float qx = pc[((size_t)b * NSD + s) * 3 + 0];
  float qy = pc[((size_t)b * NSD + s) * 3 + 1];
  float qz = pc[((size_t)b * NSD + s) * 3 + 2];
  float qq = qx * qx + qy * qy + qz * qz;
  int i0 = chunk * 250;
  float best = INFINITY; int bi = i0;
  for (int i = i0; i < i0 + 250; i++) {
    float4 p = pts[i];
    float d = qq + p.w - 2.f * (qx * p.x + qy * p.y + qz * p.z);
    if (d < best) { best = d; bi = i; }
  }
  __shared__ float rb[8][33];
  __shared__ int ri[8][33];
  rb[chunk][sl] = best; ri[chunk][sl] = bi;
  __syncthreads();
  if (tid < 32) {
    float bb = INFINITY; int ii = 0;
    for (int c = 0; c < 8; c++) {          // ascending chunk order -> first-min ties
      float v = rb[c][tid];
      if (v < bb) { bb = v; ii = ri[c][tid]; }
    }
    nn_inds[b * NSD + s0 + tid] = ii;
    float4 p = pts[ii];
    out_gp[((size_t)b * NSD + s0 + tid) * 3 + 0] = p.x;
    out_gp[((size_t)b * NSD + s0 + tid) * 3 + 1] = p.y;
    out_gp[((size_t)b * NSD + s0 + tid) * 3 + 2] = p.z;
  }
}

// ---------------------------------------------------------------- gemm128
// Y[b][o][n] = sum_i W[o][i]*X[b][i][n] + bias[o] (optional relu)
// 128x64 tile, BK=16, 256 threads, 8x4 micro-tile, register prefetch.
// fp32 on purpose: bf16/MFMA noise (~1e-4) risks argmax flips in view_scores.
template <bool RELU, bool GUARD_M>
__global__ void __launch_bounds__(256) gemm128(
    const float* __restrict__ W, const float* __restrict__ X,
    const float* __restrict__ bias, float* __restrict__ Y,
    int O, int Cin, int N) {
  int b = blockIdx.z;
  const float* Xb = X + (size_t)b * Cin * N;
  float* Yb = Y + (size_t)b * O * N;
  int m0 = blockIdx.y * 128, n0 = blockIdx.x * 64;
  __shared__ float As[16][132];  // [k][m], padded
  __shared__ float Bs[16][64];   // [k][n]
  int tid = threadIdx.x;
  int mW = tid >> 1;             // 0..127
  int kW = (tid & 1) * 8;        // 0 or 8
  int kX = tid >> 4, nX = (tid & 15) * 4;
  int ty = tid >> 4, tx = tid & 15;  // micro: rows ty*8..+8, cols tx*4..+4
  bool okm = !GUARD_M || (m0 + mW) < O;
  float4 a0, a1, bv;
  {
    const float* wp = &W[(size_t)(m0 + mW) * Cin + kW];
    a0 = okm ? *(const float4*)wp : make_float4(0.f, 0.f, 0.f, 0.f);
    a1 = okm ? *(const float4*)(wp + 4) : make_float4(0.f, 0.f, 0.f, 0.f);
    bv = *(const float4*)&Xb[(size_t)kX * N + n0 + nX];
  }
  float acc[8][4] = {};
  for (int k0 = 0; k0 < Cin; k0 += 16) {
    __syncthreads();
    As[kW + 0][mW] = a0.x; As[kW + 1][mW] = a0.y;
    As[kW + 2][mW] = a0.z; As[kW + 3][mW] = a0.w;
    As[kW + 4][mW] = a1.x; As[kW + 5][mW] = a1.y;
    As[kW + 6][mW] = a1.z; As[kW + 7][mW] = a1.w;
    *(float4*)&Bs[kX][nX] = bv;
    __syncthreads();
    if (k0 + 16 < Cin) {
      const float* wp = &W[(size_t)(m0 + mW) * Cin + k0 + 16 + kW];
      a0 = okm ? *(const float4*)wp : make_float4(0.f, 0.f, 0.f, 0.f);
      a1 = okm ? *(const float4*)(wp + 4) : make_float4(0.f, 0.f, 0.f, 0.f);
      bv = *(const float4*)&Xb[(size_t)(k0 + 16 + kX) * N + n0 + nX];
    }
#pragma unroll
    for (int kk = 0; kk < 16; kk++) {
      float4 x0 = *(const float4*)&As[kk][ty * 8];
      float4 x1 = *(const float4*)&As[kk][ty * 8 + 4];
      float4 y = *(const float4*)&Bs[kk][tx * 4];
      acc[0][0] = fmaf(x0.x, y.x, acc[0][0]); acc[0][1] = fmaf(x0.x, y.y, acc[0][1]);
      acc[0][2] = fmaf(x0.x, y.z, acc[0][2]); acc[0][3] = fmaf(x0.x, y.w, acc[0][3]);
      acc[1][0] = fmaf(x0.y, y.x, acc[1][0]); acc[1][1] = fmaf(x0.y, y.y, acc[1][1]);
      acc[1][2] = fmaf(x0.y, y.z, acc[1][2]); acc[1][3] = fmaf(x0.y, y.w, acc[1][3]);
      acc[2][0] = fmaf(x0.z, y.x, acc[2][0]); acc[2][1] = fmaf(x0.z, y.y, acc[2][1]);
      acc[2][2] = fmaf(x0.z, y.z, acc[2][2]); acc[2][3] = fmaf(x0.z, y.w, acc[2][3]);
      acc[3][0] = fmaf(x0.w, y.x, acc[3][0]); acc[3][1] = fmaf(x0.w, y.y, acc[3][1]);
      acc[3][2] = fmaf(x0.w, y.z, acc[3][2]); acc[3][3] = fmaf(x0.w, y.w, acc[3][3]);
      acc[4][0] = fmaf(x1.x, y.x, acc[4][0]); acc[4][1] = fmaf(x1.x, y.y, acc[4][1]);
      acc[4][2] = fmaf(x1.x, y.z, acc[4][2]); acc[4][3] = fmaf(x1.x, y.w, acc[4][3]);
      acc[5][0] = fmaf(x1.y, y.x, acc[5][0]); acc[5][1] = fmaf(x1.y, y.y, acc[5][1]);
      acc[5][2] = fmaf(x1.y, y.z, acc[5][2]); acc[5][3] = fmaf(x1.y, y.w, acc[5][3]);
      acc[6][0] = fmaf(x1.z, y.x, acc[6][0]); acc[6][1] = fmaf(x1.z, y.y, acc[6][1]);
      acc[6][2] = fmaf(x1.z, y.z, acc[6][2]); acc[6][3] = fmaf(x1.z, y.w, acc[6][3]);
      acc[7][0] = fmaf(x1.w, y.x, acc[7][0]); acc[7][1] = fmaf(x1.w, y.y, acc[7][1]);
      acc[7][2] = fmaf(x1.w, y.z, acc[7][2]); acc[7][3] = fmaf(x1.w, y.w, acc[7][3]);
    }
  }
#pragma unroll
  for (int i = 0; i < 8; i++) {
    int m = m0 + ty * 8 + i;
    if (GUARD_M && m >= O) break;
    float bi = bias[m];
    float4 v;
    v.x = acc[i][0] + bi; v.y = acc[i][1] + bi;
    v.z = acc[i][2] + bi; v.w = acc[i][3] + bi;
    if (RELU) {
      v.x = fmaxf(v.x, 0.f); v.y = fmaxf(v.y, 0.f);
      v.z = fmaxf(v.z, 0.f); v.w = fmaxf(v.w, 0.f);
    }
    *(float4*)&Yb[(size_t)m * N + n0 + (tx << 2)] = v;
  }
}

// ---------------------------------------------------------------- gemm_k (64x64; for skinny sw2)
template <bool RELU, bool GUARD_M>
__global__ void __launch_bounds__(256) gemm_k(
    const float* __restrict__ W, const float* __restrict__ X,
    const float* __restrict__ bias, float* __restrict__ Y,
    int O, int Cin, int N) {
  int b = blockIdx.z;
  const float* Xb = X + (size_t)b * Cin * N;
  float* Yb = Y + (size_t)b * O * N;
  int m0 = blockIdx.y * 64, n0 = blockIdx.x * 64;
  __shared__ float As[16][68];
  __shared__ float Bs[16][64];
  int tid = threadIdx.x;
  int mW = tid >> 2, kW = (tid & 3) * 4;
  int kX = tid >> 4, nX = (tid & 15) * 4;
  int ty = tid >> 4, tx = tid & 15;
  float acc[4][4] = {};
  for (int k0 = 0; k0 < Cin; k0 += 16) {
    float4 wv;
    if (!GUARD_M || (m0 + mW) < O)
      wv = *(const float4*)&W[(size_t)(m0 + mW) * Cin + k0 + kW];
    else
      wv = make_float4(0.f, 0.f, 0.f, 0.f);
    As[kW + 0][mW] = wv.x; As[kW + 1][mW] = wv.y;
    As[kW + 2][mW] = wv.z; As[kW + 3][mW] = wv.w;
    *(float4*)&Bs[kX][nX] = *(const float4*)&Xb[(size_t)(k0 + kX) * N + n0 + nX];
    __syncthreads();
#pragma unroll
    for (int kk = 0; kk < 16; kk++) {
      float4 a = *(const float4*)&As[kk][ty << 2];
      float4 bv = *(const float4*)&Bs[kk][tx << 2];
      acc[0][0] = fmaf(a.x, bv.x, acc[0][0]); acc[0][1] = fmaf(a.x, bv.y, acc[0][1]);
      acc[0][2] = fmaf(a.x, bv.z, acc[0][2]); acc[0][3] = fmaf(a.x, bv.w, acc[0][3]);
      acc[1][0] = fmaf(a.y, bv.x, acc[1][0]); acc[1][1] = fmaf(a.y, bv.y, acc[1][1]);
      acc[1][2] = fmaf(a.y, bv.z, acc[1][2]); acc[1][3] = fmaf(a.y, bv.w, acc[1][3]);
      acc[2][0] = fmaf(a.z, bv.x, acc[2][0]); acc[2][1] = fmaf(a.z, bv.y, acc[2][1]);
      acc[2][2] = fmaf(a.z, bv.z, acc[2][2]); acc[2][3] = fmaf(a.z, bv.w, acc[2][3]);
      acc[3][0] = fmaf(a.w, bv.x, acc[3][0]); acc[3][1] = fmaf(a.w, bv.y, acc[3][1]);
      acc[3][2] = fmaf(a.w, bv.z, acc[3][2]); acc[3][3] = fmaf(a.w, bv.w, acc[3][3]);
    }
    __syncthreads();
  }
#pragma unroll
  for (int i = 0; i < 4; i++) {
    int m = m0 + ty * 4 + i;
    if (GUARD_M && m >= O) break;
    float bi = bias[m];
    float4 v;
    v.x = acc[i][0] + bi; v.y = acc[i][1] + bi;
    v.z = acc[i][2] + bi; v.w = acc[i][3] + bi;
    if (RELU) {
      v.x = fmaxf(v.x, 0.f); v.y = fmaxf(v.y, 0.f);
      v.z = fmaxf(v.z, 0.f); v.w = fmaxf(v.w, 0.f);
    }
    *(float4*)&Yb[(size_t)m * N + n0 + (tx << 2)] = v;
  }
}

// ---------------------------------------------------------------- k_argmax
__global__ void __launch_bounds__(256) k_argmax(
    const float* __restrict__ vs_t, const float* __restrict__ views_rot,
    const float* __restrict__ Rsel, int* __restrict__ tv_inds,
    float* __restrict__ o_vprot, float* __restrict__ o_trot) {
  int b = blockIdx.y;
  int n = blockIdx.x * 256 + threadIdx.x;
  const float* src = vs_t + (size_t)b * NV * NSD + n;
  float best = src[0]; int bi = 0;
  for (int v = 1; v < NV; v++) {
    float val = src[(size_t)v * NSD];
    if (val > best) { best = val; bi = v; }
  }
  tv_inds[b * NSD + n] = bi;
  const float* vr = views_rot + bi * 9;
  float* o1 = o_vprot + ((size_t)b * NSD + n) * 9;
  const float* rs = Rsel + (b * NV + bi) * 9;
  float* o4 = o_trot + ((size_t)b * NSD + n) * 9;
#pragma unroll
  for (int i = 0; i < 9; i++) { o1[i] = vr[i]; o4[i] = rs[i]; }
}

// ---------------------------------------------------------------- k_transpose_vs
__global__ void k_transpose_vs(const float* __restrict__ vs_t, float* __restrict__ out) {
  __shared__ float tile[32][33];
  int b = blockIdx.z;
  int v0 = blockIdx.x * 32, n0 = blockIdx.y * 32;
  const float* src = vs_t + (size_t)b * NV * NSD;
  for (int i = threadIdx.y; i < 32; i += 8) {
    int v = v0 + i;
    if (v < NV) tile[i][threadIdx.x] = src[(size_t)v * NSD + n0 + threadIdx.x];
  }
  __syncthreads();
  for (int i = threadIdx.y; i < 32; i += 8) {
    int n = n0 + i;
    int v = v0 + threadIdx.x;
    if (v < NV) out[((size_t)b * NSD + n) * NV + v] = tile[threadIdx.x][i];
  }
}

// ---------------------------------------------------------------- k_f2
__global__ void __launch_bounds__(256) k_f2(const float* __restrict__ f2,
                                            float* __restrict__ gsp,
                                            float* __restrict__ gwp) {
  __shared__ float tile[96][65];
  int b = blockIdx.y, n0 = blockIdx.x * 64;
  const float* src = f2 + (size_t)b * 96 * NSD;
  for (int idx = threadIdx.x; idx < 96 * 64; idx += 256) {
    int ch = idx >> 6, j = idx & 63;
    tile[ch][j] = src[(size_t)ch * NSD + n0 + j];
  }
  __syncthreads();
  for (int idx = threadIdx.x; idx < 64 * 48; idx += 256) {
    int j = idx / 48, ad = idx % 48;
    size_t o = ((size_t)b * NSD + n0 + j) * 48 + ad;
    gsp[o] = tile[ad][j];
    gwp[o] = tile[48 + ad][j];
  }
}

// ---------------------------------------------------------------- k_grasp
__global__ void __launch_bounds__(256) k_grasp(
    const float* __restrict__ gscores, const float* __restrict__ goffsets,
    const int* __restrict__ nn_inds, const int* __restrict__ tv_inds,
    const int* __restrict__ view_inds, float* __restrict__ o_grsp,
    float* __restrict__ o_twd, float* __restrict__ raw) {
  int b = blockIdx.y, s = blockIdx.x, tid = threadIdx.x;
  __shared__ int vi[NV];
  for (int v = tid; v < NV; v += 256) vi[v] = view_inds[b * NV + v];
  __syncthreads();
  int nn = nn_inds[b * NSD + s];
  int tv = tv_inds[b * NSD + s];
  int vit = vi[tv];
  const float* srow = gscores + ((size_t)(b * NGP + nn)) * ROWLEN;
  const float* wrow = goffsets + ((size_t)(b * NGP + nn)) * ROWLEN;
  if (tid < 48) {
    float sc = srow[vit * 48 + tid];
    float wd = wrow[vit * 48 + tid];
    bool m = (sc > 0.f) && (wd <= 0.1f);
    o_twd[((size_t)b * NSD + s) * 48 + tid] = wd;
    raw[((size_t)b * NSD + s) * 48 + tid] = m ? sc : 0.f;
  }
  __shared__ float g[NV];
  for (int v = tid; v < NV; v += 256) {
    int vv = vi[v];
    const float4* p = (const float4*)(srow + vv * 48);
    int cnt = 0;
#pragma unroll
    for (int q = 0; q < 12; q++) {
      float4 x = p[q];
      cnt += (x.x > 0.f && x.x <= 0.6f);
      cnt += (x.y > 0.f && x.y <= 0.6f);
      cnt += (x.z > 0.f && x.z <= 0.6f);
      cnt += (x.w > 0.f && x.w <= 0.6f);
    }
    g[v] = (float)cnt / 48.0f;
  }
  __syncthreads();
  float mx = -INFINITY, mn = INFINITY;
  for (int v = tid; v < NV; v += 256) { mx = fmaxf(mx, g[v]); mn = fminf(mn, g[v]); }
  for (int off = 32; off; off >>= 1) {
    mx = fmaxf(mx, __shfl_down(mx, off));
    mn = fminf(mn, __shfl_down(mn, off));
  }
  __shared__ float wmx[4], wmn[4];
  int wid = tid >> 6, lane = tid & 63;
  if (lane == 0) { wmx[wid] = mx; wmn[wid] = mn; }
  __syncthreads();
  if (tid == 0) {
    mx = fmaxf(fmaxf(wmx[0], wmx[1]), fmaxf(wmx[2], wmx[3]));
    mn = fminf(fminf(wmn[0], wmn[1]), fminf(wmn[2], wmn[3]));
    wmx[0] = mx; wmn[0] = mn;
  }
  __syncthreads();
  mx = wmx[0]; mn = wmn[0];
  float denom = mx - mn + 1e-8f;
  float* og = o_grsp + ((size_t)b * NSD + s) * NV;
  for (int v = tid; v < NV; v += 256) og[v] = (g[v] - mn) / denom;
}

// ---------------------------------------------------------------- k_reduce
__global__ void __launch_bounds__(256) k_reduce(const float* __restrict__ raw,
                                                int n, int* __restrict__ mmx) {
  float mx = -INFINITY, mn = INFINITY;
  for (int i = blockIdx.x * 256 + threadIdx.x; i < n; i += gridDim.x * 256) {
    float v = raw[i];
    mx = fmaxf(mx, v);
    if (v > 0.f) mn = fminf(mn, v);
  }
  for (int off = 32; off; off >>= 1) {
    mx = fmaxf(mx, __shfl_down(mx, off));
    mn = fminf(mn, __shfl_down(mn, off));
  }
  __shared__ float smx[4], smn[4];
  int wid = threadIdx.x >> 6, lane = threadIdx.x & 63;
  if (lane == 0) { smx[wid] = mx; smn[wid] = mn; }
  __syncthreads();
  if (threadIdx.x == 0) {
    mx = fmaxf(fmaxf(smx[0], smx[1]), fmaxf(smx[2], smx[3]));
    mn = fminf(fminf(smn[0], smn[1]), fminf(smn[2], smn[3]));
    atomicMax(&mmx[0], __float_as_int(mx));   // values >= 0: int order == float order
    if (mn != INFINITY) atomicMin(&mmx[1], __float_as_int(mn));
  }
}

// ---------------------------------------------------------------- k_topsc
__global__ void k_topsc(const float* __restrict__ raw, const int* __restrict__ mmx,
                        float* __restrict__ out, int n) {
  int i = blockIdx.x * 256 + threadIdx.x;
  if (i >= n) return;
  float sc = raw[i];
  float umax = __int_as_float(mmx[0]);
  float umin = __int_as_float(mmx[1]);
  float denom = logf(umax / umin) + 1e-8f;
  float val = logf(umax / sc) / denom;
  out[i] = (sc > 0.f) ? val : sc;
}

// ================================================================ launch
extern "C" void kernel_launch(void* const* d_in, const int* in_sizes, int n_in,
                              void* d_out, int out_size, void* d_ws, size_t ws_size,
                              hipStream_t stream) {
  const float* seed_features = (const float*)d_in[0];
  const float* point_clouds  = (const float*)d_in[1];
  const float* object_pose   = (const float*)d_in[2];
  const float* grasp_points  = (const float*)d_in[3];
  const float* grasp_labels  = (const float*)d_in[4];
  const float* grasp_offsets = (const float*)d_in[5];
  const float* aw1_w = (const float*)d_in[6];
  const float* aw1_b = (const float*)d_in[7];
  const float* aw2_w = (const float*)d_in[8];
  const float* aw2_b = (const float*)d_in[9];
  const float* aw3_w = (const float*)d_in[10];
  const float* aw3_b = (const float*)d_in[11];
  const float* sw1_w = (const float*)d_in[12];
  const float* sw1_b = (const float*)d_in[13];
  const float* sw2_w = (const float*)d_in[14];
  const float* sw2_b = (const float*)d_in[15];

  float* out = (float*)d_out;
  float* o_vs    = out;                      // (B,NS,300)
  float* o_vprot = o_vs + NB * NSD * NV;     // (B,NS,3,3)
  float* o_gsp   = o_vprot + NB * NSD * 9;   // (B,NS,12,4)
  float* o_gwp   = o_gsp + NB * NSD * 48;
  float* o_trot  = o_gwp + NB * NSD * 48;    // (B,NS,3,3)
  float* o_tsc   = o_trot + NB * NSD * 9;
  float* o_twd   = o_tsc + NB * NSD * 48;
  float* o_grsp  = o_twd + NB * NSD * 48;    // (B,NS,300)
  float* o_gp    = o_grsp + NB * NSD * NV;   // (B,NS,3)

  float* w = (float*)d_ws;
  float* res1 = w; w += NB * NC * NSD;       // reused as f1
  float* res2 = w; w += NB * NC * NSD;
  float* vs_t = w; w += NB * NV * NSD;
  float* f2   = w; w += NB * 96 * NSD;
  float* views = w; w += 960;
  float* views_rot = w; w += 2720;
  float4* gpt4 = (float4*)w; w += NB * NGP * 4;
  float* Rsel = w; w += NB * NV * 9;
  float* raw  = w; w += NB * NSD * 48;
  int* view_inds = (int*)w; w += NB * NV;
  int* nn_inds   = (int*)w; w += NB * NSD;
  int* tv_inds   = (int*)w; w += NB * NSD;
  int* mmx       = (int*)w; w += 8;

  k_setup<<<1, 512, 0, stream>>>(views, views_rot, mmx);
  k_batch_setup<<<NB, 512, 0, stream>>>(object_pose, views, views_rot, view_inds, Rsel);
  k_gp_trans<<<(NB * NGP + 255) / 256, 256, 0, stream>>>(object_pose, grasp_points, gpt4);
  k_nn<<<dim3(NSD / 32, NB), 256, 0, stream>>>(point_clouds, gpt4, nn_inds, o_gp);

  gemm128<true, false><<<dim3(NSD / 64, NC / 128, NB), 256, 0, stream>>>(
      aw1_w, seed_features, aw1_b, res1, NC, NC, NSD);
  gemm128<true, false><<<dim3(NSD / 64, NC / 128, NB), 256, 0, stream>>>(
      aw2_w, res1, aw2_b, res2, NC, NC, NSD);
  gemm128<false, true><<<dim3(NSD / 64, (NV + 127) / 128, NB), 256, 0, stream>>>(
      aw3_w, res2, aw3_b, vs_t, NV, NC, NSD);
  gemm128<true, false><<<dim3(NSD / 64, NC / 128, NB), 256, 0, stream>>>(
      sw1_w, res2, sw1_b, res1, NC, NC, NSD);
  gemm_k<false, true><<<dim3(NSD / 64, 2, NB), 256, 0, stream>>>(
      sw2_w, res1, sw2_b, f2, 96, NC, NSD);

  k_argmax<<<dim3(NSD / 256, NB), 256, 0, stream>>>(vs_t, views_rot, Rsel, tv_inds,
                                                    o_vprot, o_trot);
  k_transpose_vs<<<dim3((NV + 31) / 32, NSD / 32, NB), dim3(32, 8), 0, stream>>>(vs_t, o_vs);
  k_f2<<<dim3(NSD / 64, NB), 256, 0, stream>>>(f2, o_gsp, o_gwp);
  k_grasp<<<dim3(NSD, NB), 256, 0, stream>>>(grasp_labels, grasp_offsets, nn_inds,
                                             tv_inds, view_inds, o_grsp, o_twd, raw);
  k_reduce<<<256, 256, 0, stream>>>(raw, NB * NSD * 48, mmx);
  k_topsc<<<(NB * NSD * 48 + 255) / 256, 256, 0, stream>>>(raw, mmx, o_tsc, NB * NSD * 48);
}